// Round 1
// baseline (64827.020 us; speedup 1.0000x reference)
//
#include <hip/hip_runtime.h>
#include <stdint.h>

typedef __attribute__((ext_vector_type(8))) short short8;
typedef __attribute__((ext_vector_type(4))) float fl4;
typedef __attribute__((ext_vector_type(4))) unsigned short bfq;
typedef __attribute__((ext_vector_type(8))) unsigned short us8;

#define SAT_HI 1.0e6f

// ---- workspace layout (bytes) ----
#define WFRAG_OFF 0ull            // 32 MB : W bf16 fragments, MFMA order
#define Z_OFF     33554432ull     // 512 KB: z [64][4096] bf16
#define PART_OFF  34078720ull     // 8 MB  : partials [8][64][4096] f32
#define DSC_OFF   42467328ull     // 2 MB  : decode partials [4][4][64][512] f32
#define CNT_OFF   44564480ull     // barrier counter

__device__ __forceinline__ unsigned short f2bf(float f) {
  unsigned u = __float_as_uint(f);
  u += 0x7fffu + ((u >> 16) & 1u);   // RNE
  return (unsigned short)(u >> 16);
}
__device__ __forceinline__ float clipf(float x) {
  return fminf(fmaxf(x, 0.0f), SAT_HI);
}

__device__ __forceinline__ void gload16(const void* g, void* l) {
  __builtin_amdgcn_global_load_lds(
      (const __attribute__((address_space(1))) void*)g,
      (__attribute__((address_space(3))) void*)l, 16, 0, 0);
}

// device-scope grid barrier: monotonic counter, target = epoch*256
__device__ __forceinline__ void gbar(int* cnt, int target) {
  __threadfence();
  __syncthreads();
  if (threadIdx.x == 0) {
    __hip_atomic_fetch_add(cnt, 1, __ATOMIC_RELEASE, __HIP_MEMORY_SCOPE_AGENT);
    while (__hip_atomic_load(cnt, __ATOMIC_ACQUIRE, __HIP_MEMORY_SCOPE_AGENT) < target)
      __builtin_amdgcn_s_sleep(1);
  }
  __syncthreads();
  __threadfence();
}

// ---- pack W (f32 [N][N]) into bf16 MFMA B-fragments ----
// wfrag granule u = [g:8][w:2][nt:1][ki:4][lane:6], 8 bf16 each.
// lane supplies col n = ng*128 + w*32 + nt*16 + (lane&15),
//               k  = sg*512 + ki*32 + (lane>>4)*8 + j   (B[k][n] = W[n][k])
__global__ __launch_bounds__(256) void prep_kernel(const float* __restrict__ W,
                                                   unsigned short* __restrict__ wfrag) {
  unsigned u = blockIdx.x * 256u + threadIdx.x;        // < 2097152
  unsigned lane = u & 63u;
  unsigned ki = (u >> 6) & 15u;
  unsigned nt = (u >> 10) & 1u;
  unsigned w = (u >> 11) & 3u;
  unsigned g = u >> 13;
  unsigned ng = g >> 3, sg = g & 7u;
  unsigned n = ng * 128u + w * 32u + nt * 16u + (lane & 15u);
  unsigned k = sg * 512u + ki * 32u + (lane >> 4) * 8u;
  const float* src = W + (size_t)n * 4096u + k;
  fl4 s0 = *(const fl4*)(src);
  fl4 s1 = *(const fl4*)(src + 4);
  us8 o;
  o[0] = f2bf(s0[0]); o[1] = f2bf(s0[1]); o[2] = f2bf(s0[2]); o[3] = f2bf(s0[3]);
  o[4] = f2bf(s1[0]); o[5] = f2bf(s1[1]); o[6] = f2bf(s1[2]); o[7] = f2bf(s1[3]);
  *(us8*)(wfrag + (size_t)u * 8u) = o;
}

__global__ __launch_bounds__(256, 1) void persist_kernel(
    const float* __restrict__ xin,     // [C][B][T]
    const float* __restrict__ state0,  // [B][N]
    const float* __restrict__ mask,    // [N]
    const float* __restrict__ enc,     // [C][N]
    const float* __restrict__ bias,    // [N]
    const float* __restrict__ decw,    // [C][N]
    const unsigned short* __restrict__ wfrag,
    unsigned short* __restrict__ zbuf, // [B][N] bf16
    float* __restrict__ part,          // [8][B][N] f32
    float* __restrict__ dsc,           // [4][4][B][T] f32
    int* __restrict__ cnt) {
  __shared__ unsigned short zs[64 * 512];  // 64 KB z slice, swizzled cols
  __shared__ float dred[16];

  const int tid = threadIdx.x;
  const int wave = tid >> 6;
  const int lane = tid & 63;
  const int lo = lane & 15, hi = lane >> 4, rx = lane & 7;
  const int g = blockIdx.x;
  const int ng = g >> 3, sg = g & 7;   // sg = g%8 -> same z-slice blocks share an XCD

  // persistent W fragments: 32 x short8 = 128 VGPRs
  short8 wf[32];
  {
    const short8* wp = (const short8*)wfrag + ((size_t)(g * 4 + wave) * 32u) * 64u + lane;
#pragma unroll
    for (int f = 0; f < 32; ++f) wf[f] = wp[(size_t)f * 64u];
  }

  // phase-B role: row b = g&63, n-quarter q = g>>6; 4 n's per thread
  const int pb_b = g & 63, pb_q = g >> 6;
  const int n0 = pb_q * 1024 + tid * 4;
  const fl4 m4 = *(const fl4*)(mask + n0);
  const fl4 bi4 = *(const fl4*)(bias + n0);
  const fl4 e0 = *(const fl4*)(enc + n0);
  const fl4 e1 = *(const fl4*)(enc + 4096 + n0);
  const fl4 e2 = *(const fl4*)(enc + 8192 + n0);
  const fl4 e3 = *(const fl4*)(enc + 12288 + n0);
  const fl4 d0 = *(const fl4*)(decw + n0);
  const fl4 d1 = *(const fl4*)(decw + 4096 + n0);
  const fl4 d2 = *(const fl4*)(decw + 8192 + n0);
  const fl4 d3 = *(const fl4*)(decw + 12288 + n0);
  const float* xb = xin + pb_b * 512;  // x[c][pb_b][t] = xb[c*32768 + t]

  int ep = 0;

  // prologue: z0 = state + mask*ext0
  {
    fl4 st = *(const fl4*)(state0 + (size_t)pb_b * 4096u + n0);
    float x0 = xb[0], x1 = xb[32768], x2 = xb[65536], x3 = xb[98304];
    fl4 zv = st + m4 * (x0 * e0 + x1 * e1 + x2 * e2 + x3 * e3);
    bfq zo;
    zo[0] = f2bf(zv[0]); zo[1] = f2bf(zv[1]); zo[2] = f2bf(zv[2]); zo[3] = f2bf(zv[3]);
    *(bfq*)(zbuf + (size_t)pb_b * 4096u + n0) = zo;
  }
  gbar(cnt, (++ep) * 256);

  for (int t = 0; t < 512; ++t) {
    // ================= phase A: partial GEMM =================
    {
      // z slice -> LDS, source pre-swizzled so reads are bank-even (rule #21)
      const char* zg = (const char*)zbuf + sg * 1024;
      char* zls = (char*)zs;
#pragma unroll
      for (int i = 0; i < 16; ++i) {
        const int brow = i * 4 + wave;
        gload16(zg + brow * 8192 + ((lane ^ (brow & 7)) << 4), zls + brow * 1024);
      }
      __syncthreads();

      fl4 acc[4][2];
#pragma unroll
      for (int mt = 0; mt < 4; ++mt) {
        acc[mt][0] = (fl4){0.f, 0.f, 0.f, 0.f};
        acc[mt][1] = (fl4){0.f, 0.f, 0.f, 0.f};
      }
      const char* zsc = (const char*)zs;
      const int abase = lo * 1024;
#pragma unroll
      for (int ki = 0; ki < 16; ++ki) {
        const int sw = abase + ((((ki << 2) + hi) ^ rx) << 4);
        short8 a0 = *(const short8*)(zsc + sw);
        short8 a1 = *(const short8*)(zsc + sw + 16384);
        short8 a2 = *(const short8*)(zsc + sw + 32768);
        short8 a3 = *(const short8*)(zsc + sw + 49152);
        acc[0][0] = __builtin_amdgcn_mfma_f32_16x16x32_bf16(a0, wf[ki], acc[0][0], 0, 0, 0);
        acc[1][0] = __builtin_amdgcn_mfma_f32_16x16x32_bf16(a1, wf[ki], acc[1][0], 0, 0, 0);
        acc[2][0] = __builtin_amdgcn_mfma_f32_16x16x32_bf16(a2, wf[ki], acc[2][0], 0, 0, 0);
        acc[3][0] = __builtin_amdgcn_mfma_f32_16x16x32_bf16(a3, wf[ki], acc[3][0], 0, 0, 0);
        acc[0][1] = __builtin_amdgcn_mfma_f32_16x16x32_bf16(a0, wf[16 + ki], acc[0][1], 0, 0, 0);
        acc[1][1] = __builtin_amdgcn_mfma_f32_16x16x32_bf16(a1, wf[16 + ki], acc[1][1], 0, 0, 0);
        acc[2][1] = __builtin_amdgcn_mfma_f32_16x16x32_bf16(a2, wf[16 + ki], acc[2][1], 0, 0, 0);
        acc[3][1] = __builtin_amdgcn_mfma_f32_16x16x32_bf16(a3, wf[16 + ki], acc[3][1], 0, 0, 0);
      }
      float* pb = part + (size_t)sg * 64u * 4096u;
      const int nb = ng * 128 + wave * 32 + lo;
#pragma unroll
      for (int mt = 0; mt < 4; ++mt)
#pragma unroll
        for (int nt2 = 0; nt2 < 2; ++nt2)
#pragma unroll
          for (int r = 0; r < 4; ++r) {
            const int b = mt * 16 + hi * 4 + r;
            pb[(size_t)b * 4096u + nb + nt2 * 16] = acc[mt][nt2][r];
          }
    }
    gbar(cnt, (++ep) * 256);

    // ================= phase B: reduce + state + decode =================
    {
      fl4 y = (fl4){0.f, 0.f, 0.f, 0.f};
#pragma unroll
      for (int s = 0; s < 8; ++s)
        y += *(const fl4*)(part + (size_t)(s * 64 + pb_b) * 4096u + n0);
      fl4 sn;
      sn[0] = m4[0] * (bi4[0] + clipf(y[0]));
      sn[1] = m4[1] * (bi4[1] + clipf(y[1]));
      sn[2] = m4[2] * (bi4[2] + clipf(y[2]));
      sn[3] = m4[3] * (bi4[3] + clipf(y[3]));

      float dc0 = sn[0] * d0[0] + sn[1] * d0[1] + sn[2] * d0[2] + sn[3] * d0[3];
      float dc1 = sn[0] * d1[0] + sn[1] * d1[1] + sn[2] * d1[2] + sn[3] * d1[3];
      float dc2 = sn[0] * d2[0] + sn[1] * d2[1] + sn[2] * d2[2] + sn[3] * d2[3];
      float dc3 = sn[0] * d3[0] + sn[1] * d3[1] + sn[2] * d3[2] + sn[3] * d3[3];
#pragma unroll
      for (int off = 32; off > 0; off >>= 1) {
        dc0 += __shfl_xor(dc0, off);
        dc1 += __shfl_xor(dc1, off);
        dc2 += __shfl_xor(dc2, off);
        dc3 += __shfl_xor(dc3, off);
      }
      if (lane == 0) {
        dred[wave * 4 + 0] = dc0; dred[wave * 4 + 1] = dc1;
        dred[wave * 4 + 2] = dc2; dred[wave * 4 + 3] = dc3;
      }
      __syncthreads();
      if (tid < 4) {
        float s = dred[tid] + dred[4 + tid] + dred[8 + tid] + dred[12 + tid];
        dsc[((size_t)(pb_q * 4 + tid) * 64u + pb_b) * 512u + t] = s;
      }
      if (t < 511) {
        float x0 = xb[t + 1], x1 = xb[32768 + t + 1];
        float x2 = xb[65536 + t + 1], x3 = xb[98304 + t + 1];
        fl4 zv = sn + m4 * (x0 * e0 + x1 * e1 + x2 * e2 + x3 * e3);
        bfq zo;
        zo[0] = f2bf(zv[0]); zo[1] = f2bf(zv[1]); zo[2] = f2bf(zv[2]); zo[3] = f2bf(zv[3]);
        *(bfq*)(zbuf + (size_t)pb_b * 4096u + n0) = zo;
        gbar(cnt, (++ep) * 256);
      }
    }
  }
}

__global__ __launch_bounds__(256) void final_kernel(const float* __restrict__ dsc,
                                                    const float* __restrict__ decb,
                                                    float* __restrict__ out) {
  const unsigned u = blockIdx.x * 256u + threadIdx.x;  // < 131072
  const unsigned t = u & 511u, b = (u >> 9) & 63u, c = u >> 15;
  float s = decb[c];
#pragma unroll
  for (int q = 0; q < 4; ++q)
    s += dsc[((size_t)(q * 4 + c) * 64u + b) * 512u + t];
  out[u] = clipf(s);
}

extern "C" void kernel_launch(void* const* d_in, const int* in_sizes, int n_in,
                              void* d_out, int out_size, void* d_ws, size_t ws_size,
                              hipStream_t stream) {
  const float* xin  = (const float*)d_in[0];
  const float* st   = (const float*)d_in[1];
  const float* mask = (const float*)d_in[2];
  const float* W    = (const float*)d_in[3];
  const float* enc  = (const float*)d_in[4];
  const float* bias = (const float*)d_in[5];
  const float* decw = (const float*)d_in[6];
  const float* decb = (const float*)d_in[7];
  char* ws = (char*)d_ws;
  unsigned short* wfrag = (unsigned short*)(ws + WFRAG_OFF);
  unsigned short* zbuf  = (unsigned short*)(ws + Z_OFF);
  float* part = (float*)(ws + PART_OFF);
  float* dsc  = (float*)(ws + DSC_OFF);
  int* cnt    = (int*)(ws + CNT_OFF);

  hipMemsetAsync(cnt, 0, 64, stream);
  prep_kernel<<<8192, 256, 0, stream>>>(W, wfrag);
  persist_kernel<<<256, 256, 0, stream>>>(xin, st, mask, enc, bias, decw,
                                          wfrag, zbuf, part, dsc, cnt);
  final_kernel<<<512, 256, 0, stream>>>(dsc, decb, (float*)d_out);
}

// Round 2
// 18350.011 us; speedup vs baseline: 3.5328x; 3.5328x over previous
//
#include <hip/hip_runtime.h>
#include <stdint.h>

typedef __attribute__((ext_vector_type(8))) short short8;
typedef __attribute__((ext_vector_type(4))) float fl4;
typedef __attribute__((ext_vector_type(2))) float fl2;
typedef __attribute__((ext_vector_type(8))) unsigned short us8;

#define SAT_HI 1.0e6f

// ---- workspace layout (bytes) ----
#define WFRAG_OFF 0ull            // 32 MB : W bf16 B-fragments, MFMA order
#define Z_OFF     33554432ull     // 3 x 512 KB : z triple buffer, bf16 [64][4096]
#define ZELEMS    262144u         // 64*4096
#define DSC_OFF   35127296ull     // 512 KB : decode accum [C=4][B=64][T=512] f32
#define CNT_OFF   35651584ull     // barrier counter

__device__ __forceinline__ unsigned short f2bf(float f) {
  unsigned u = __float_as_uint(f);
  u += 0x7fffu + ((u >> 16) & 1u);   // RNE
  return (unsigned short)(u >> 16);
}
__device__ __forceinline__ float clipf(float x) {
  return fminf(fmaxf(x, 0.0f), SAT_HI);
}

// grid barrier: relaxed spin, ONE release-add + ONE acquire-load per block.
// (previous version did an ACQUIRE load per poll -> continuous L2 invalidation)
__device__ __forceinline__ void gbar(int* cnt, int target) {
  __syncthreads();                  // drains vmcnt: block's stores are in L2
  if (threadIdx.x == 0) {
    __hip_atomic_fetch_add(cnt, 1, __ATOMIC_RELEASE, __HIP_MEMORY_SCOPE_AGENT);
    while (__hip_atomic_load(cnt, __ATOMIC_RELAXED, __HIP_MEMORY_SCOPE_AGENT) < target)
      __builtin_amdgcn_s_sleep(2);
    (void)__hip_atomic_load(cnt, __ATOMIC_ACQUIRE, __HIP_MEMORY_SCOPE_AGENT);
  }
  __syncthreads();
}

// ---- pack W (f32 [N][N]) into bf16 MFMA B-fragments, column-distributed ----
// granule u = [g:8][w:3][ki:4][lane:6]; block g owns cols [16g,16g+16), wave w
// owns K-eighth [512w,512w+512). lane: n = 16g+(lane&15), k = 512w+32ki+8*(lane>>4).
// B[k][n] = W[n][k]  (y = z @ W^T)
__global__ __launch_bounds__(256) void prep_kernel(const float* __restrict__ W,
                                                   unsigned short* __restrict__ wfrag) {
  unsigned u = blockIdx.x * 256u + threadIdx.x;        // < 2097152
  unsigned lane = u & 63u, lo = lane & 15u, hi = lane >> 4;
  unsigned ki = (u >> 6) & 15u;
  unsigned w = (u >> 10) & 7u;
  unsigned g = u >> 13;
  unsigned n = g * 16u + lo;
  unsigned k = w * 512u + ki * 32u + hi * 8u;
  const float* src = W + (size_t)n * 4096u + k;
  fl4 s0 = *(const fl4*)(src);
  fl4 s1 = *(const fl4*)(src + 4);
  us8 o;
  o[0] = f2bf(s0[0]); o[1] = f2bf(s0[1]); o[2] = f2bf(s0[2]); o[3] = f2bf(s0[3]);
  o[4] = f2bf(s1[0]); o[5] = f2bf(s1[1]); o[6] = f2bf(s1[2]); o[7] = f2bf(s1[3]);
  *(us8*)(wfrag + (size_t)u * 8u) = o;
}

__global__ __launch_bounds__(512, 2) void persist_kernel(
    const float* __restrict__ xin,     // [C][B][T]
    const float* __restrict__ state0,  // [B][N]
    const float* __restrict__ mask,    // [N]
    const float* __restrict__ enc,     // [C][N]
    const float* __restrict__ bias,    // [N]
    const float* __restrict__ decw,    // [C][N]
    const unsigned short* __restrict__ wfrag,
    unsigned short* __restrict__ zbuf, // [3][B][N] bf16
    float* __restrict__ dsc,           // [C][B][T] f32, atomically accumulated
    int* __restrict__ cnt) {
  __shared__ float ldsP[8][64][17];    // per-wave K-partials, pad 17 vs conflicts

  const int tid = threadIdx.x;
  const int wave = tid >> 6;           // 0..7, owns K-eighth
  const int lane = tid & 63;
  const int lo = lane & 15, hi = lane >> 4;
  const int g = blockIdx.x;            // owns cols [16g, 16g+16)

  // persistent W fragments: 16 x short8 = 64 VGPRs per thread
  short8 wf[16];
  {
    const short8* wp = (const short8*)wfrag + ((size_t)(g * 8 + wave) * 16u) * 64u + lane;
#pragma unroll
    for (int ki = 0; ki < 16; ++ki) wf[ki] = wp[(size_t)ki * 64u];
  }

  // update-phase role: row r = tid>>3 (0..63), col pair c2 = (tid&7)*2 of block's 16
  const int r = tid >> 3, c2 = (tid & 7) * 2;
  const int n0g = g * 16 + c2;
  const fl2 mk = *(const fl2*)(mask + n0g);
  const fl2 bi = *(const fl2*)(bias + n0g);
  const fl2 e0 = *(const fl2*)(enc + n0g);
  const fl2 e1 = *(const fl2*)(enc + 4096 + n0g);
  const fl2 e2 = *(const fl2*)(enc + 8192 + n0g);
  const fl2 e3 = *(const fl2*)(enc + 12288 + n0g);
  const fl2 w0 = *(const fl2*)(decw + n0g);
  const fl2 w1 = *(const fl2*)(decw + 4096 + n0g);
  const fl2 w2 = *(const fl2*)(decw + 8192 + n0g);
  const fl2 w3 = *(const fl2*)(decw + 12288 + n0g);
  const float* xp = xin + r * 512;     // x[c][r][t] = xp[c*32768 + t]
  const int kw = wave * 512;

  int ep = 0;

  // prologue: z_0 = state + mask*ext_0 (each block writes its own 16 cols)
  {
    fl2 st = *(const fl2*)(state0 + (size_t)r * 4096u + n0g);
    float x0 = xp[0], x1 = xp[32768], x2 = xp[65536], x3 = xp[98304];
    float z0 = st[0] + mk[0] * (x0 * e0[0] + x1 * e1[0] + x2 * e2[0] + x3 * e3[0]);
    float z1 = st[1] + mk[1] * (x0 * e0[1] + x1 * e1[1] + x2 * e2[1] + x3 * e3[1]);
    unsigned pack = (unsigned)f2bf(z0) | ((unsigned)f2bf(z1) << 16);
    *(unsigned*)(zbuf + (size_t)r * 4096u + n0g) = pack;
  }
  gbar(cnt, (++ep) * 256);

  int buf = 0;
  for (int t = 0; t < 512; ++t) {
    // prefetch next-step x (consumed after MFMA phase)
    float xv0 = 0.f, xv1 = 0.f, xv2 = 0.f, xv3 = 0.f;
    if (t < 511) {
      xv0 = xp[t + 1]; xv1 = xp[32768 + t + 1];
      xv2 = xp[65536 + t + 1]; xv3 = xp[98304 + t + 1];
    }

    // ---- MFMA: y_partial(own K-eighth) for [64 rows][16 cols], A direct from L2 ----
    fl4 acc0 = {0.f,0.f,0.f,0.f}, acc1 = acc0, acc2 = acc0, acc3 = acc0;
    const unsigned short* za = zbuf + (size_t)buf * ZELEMS + (size_t)lo * 4096u + kw + hi * 8;
#pragma unroll
    for (int ki = 0; ki < 16; ++ki) {
      short8 a0 = *(const short8*)(za + ki * 32);
      short8 a1 = *(const short8*)(za + ki * 32 + 16 * 4096);
      short8 a2 = *(const short8*)(za + ki * 32 + 32 * 4096);
      short8 a3 = *(const short8*)(za + ki * 32 + 48 * 4096);
      acc0 = __builtin_amdgcn_mfma_f32_16x16x32_bf16(a0, wf[ki], acc0, 0, 0, 0);
      acc1 = __builtin_amdgcn_mfma_f32_16x16x32_bf16(a1, wf[ki], acc1, 0, 0, 0);
      acc2 = __builtin_amdgcn_mfma_f32_16x16x32_bf16(a2, wf[ki], acc2, 0, 0, 0);
      acc3 = __builtin_amdgcn_mfma_f32_16x16x32_bf16(a3, wf[ki], acc3, 0, 0, 0);
    }
    // stash per-wave partials: C-layout col=lo, row=16*mt+4*hi+rr
#pragma unroll
    for (int rr = 0; rr < 4; ++rr) {
      ldsP[wave][hi * 4 + rr][lo] = acc0[rr];
      ldsP[wave][16 + hi * 4 + rr][lo] = acc1[rr];
      ldsP[wave][32 + hi * 4 + rr][lo] = acc2[rr];
      ldsP[wave][48 + hi * 4 + rr][lo] = acc3[rr];
    }
    __syncthreads();

    // ---- reduce over 8 waves + state update + decode + next z ----
    float y0 = 0.f, y1 = 0.f;
#pragma unroll
    for (int w = 0; w < 8; ++w) { y0 += ldsP[w][r][c2]; y1 += ldsP[w][r][c2 + 1]; }
    float sn0 = mk[0] * (bi[0] + clipf(y0));
    float sn1 = mk[1] * (bi[1] + clipf(y1));

    float d0 = sn0 * w0[0] + sn1 * w0[1];
    float d1 = sn0 * w1[0] + sn1 * w1[1];
    float d2 = sn0 * w2[0] + sn1 * w2[1];
    float d3 = sn0 * w3[0] + sn1 * w3[1];
    d0 += __shfl_xor(d0, 1); d0 += __shfl_xor(d0, 2); d0 += __shfl_xor(d0, 4);
    d1 += __shfl_xor(d1, 1); d1 += __shfl_xor(d1, 2); d1 += __shfl_xor(d1, 4);
    d2 += __shfl_xor(d2, 1); d2 += __shfl_xor(d2, 2); d2 += __shfl_xor(d2, 4);
    d3 += __shfl_xor(d3, 1); d3 += __shfl_xor(d3, 2); d3 += __shfl_xor(d3, 4);
    if ((tid & 7) == 0) {
      atomicAdd(dsc + r * 512 + t, d0);
      atomicAdd(dsc + 32768 + r * 512 + t, d1);
      atomicAdd(dsc + 65536 + r * 512 + t, d2);
      atomicAdd(dsc + 98304 + r * 512 + t, d3);
    }

    if (t < 511) {
      int nb = buf + 1; if (nb == 3) nb = 0;   // triple buffer: 1-step skew safe
      float z0 = sn0 + mk[0] * (xv0 * e0[0] + xv1 * e1[0] + xv2 * e2[0] + xv3 * e3[0]);
      float z1 = sn1 + mk[1] * (xv0 * e0[1] + xv1 * e1[1] + xv2 * e2[1] + xv3 * e3[1]);
      unsigned pack = (unsigned)f2bf(z0) | ((unsigned)f2bf(z1) << 16);
      *(unsigned*)(zbuf + (size_t)nb * ZELEMS + (size_t)r * 4096u + n0g) = pack;
      buf = nb;
      gbar(cnt, (++ep) * 256);
    }
  }
}

__global__ __launch_bounds__(256) void final_kernel(const float* __restrict__ dsc,
                                                    const float* __restrict__ decb,
                                                    float* __restrict__ out) {
  const unsigned u = blockIdx.x * 256u + threadIdx.x;  // < 131072, [C][B][T]
  const unsigned c = u >> 15;
  out[u] = clipf(dsc[u] + decb[c]);
}

extern "C" void kernel_launch(void* const* d_in, const int* in_sizes, int n_in,
                              void* d_out, int out_size, void* d_ws, size_t ws_size,
                              hipStream_t stream) {
  const float* xin  = (const float*)d_in[0];
  const float* st   = (const float*)d_in[1];
  const float* mask = (const float*)d_in[2];
  const float* W    = (const float*)d_in[3];
  const float* enc  = (const float*)d_in[4];
  const float* bias = (const float*)d_in[5];
  const float* decw = (const float*)d_in[6];
  const float* decb = (const float*)d_in[7];
  char* ws = (char*)d_ws;
  unsigned short* wfrag = (unsigned short*)(ws + WFRAG_OFF);
  unsigned short* zbuf  = (unsigned short*)(ws + Z_OFF);
  float* dsc = (float*)(ws + DSC_OFF);
  int* cnt   = (int*)(ws + CNT_OFF);

  hipMemsetAsync(cnt, 0, 64, stream);
  hipMemsetAsync(dsc, 0, 524288, stream);
  prep_kernel<<<8192, 256, 0, stream>>>(W, wfrag);
  persist_kernel<<<256, 512, 0, stream>>>(xin, st, mask, enc, bias, decw,
                                          wfrag, zbuf, dsc, cnt);
  final_kernel<<<512, 256, 0, stream>>>(dsc, decb, (float*)d_out);
}

// Round 3
// 11732.709 us; speedup vs baseline: 5.5253x; 1.5640x over previous
//
#include <hip/hip_runtime.h>
#include <stdint.h>

typedef __attribute__((ext_vector_type(8))) short short8;
typedef __attribute__((ext_vector_type(4))) float fl4;
typedef __attribute__((ext_vector_type(2))) float fl2;
typedef __attribute__((ext_vector_type(8))) unsigned short us8;

#define SAT_HI 1.0e6f

// ---- workspace layout (bytes) ----
#define WFRAG_OFF 0ull            // 32 MB : W bf16 B-fragments, MFMA order
#define Z_OFF     33554432ull     // 3 x 512 KB : z triple buffer, bf16 [64][4096]
#define ZELEMS    262144u         // 64*4096
#define DSC_OFF   35127296ull     // 8 x 512 KB : decode accum copies [8][C][B][T] f32
#define CNT_OFF   39321600ull     // barrier counters (gcnt line + 8 group lines)

__device__ __forceinline__ unsigned short f2bf(float f) {
  unsigned u = __float_as_uint(f);
  u += 0x7fffu + ((u >> 16) & 1u);   // RNE
  return (unsigned short)(u >> 16);
}
__device__ __forceinline__ float clipf(float x) {
  return fminf(fmaxf(x, 0.0f), SAT_HI);
}

// grid barrier, cache-op-minimal:
//  - z stores are write-through (system-relaxed) so NO buffer_wbl2 is needed;
//    arrival = vmcnt(0) drain + RELAXED add (no cache maintenance).
//  - two-level arrival: 32 adds/group line, last arriver forwards to gcnt.
//  - exactly ONE acquire (flash buffer_inv) per block per epoch.
__device__ __forceinline__ void gbar(int* cbase, int grp, int ep) {
  __syncthreads();
  if (threadIdx.x == 0) {
    int* gcnt = cbase;
    int* xcnt = cbase + 32 + grp * 32;   // 128-byte separated lines
    asm volatile("s_waitcnt vmcnt(0)" ::: "memory");
    int old = __hip_atomic_fetch_add(xcnt, 1, __ATOMIC_RELAXED, __HIP_MEMORY_SCOPE_AGENT);
    if (old == ep * 32 - 1)
      __hip_atomic_fetch_add(gcnt, 1, __ATOMIC_RELAXED, __HIP_MEMORY_SCOPE_AGENT);
    while (__hip_atomic_load(gcnt, __ATOMIC_RELAXED, __HIP_MEMORY_SCOPE_AGENT) < ep * 8)
      __builtin_amdgcn_s_sleep(2);
    (void)__hip_atomic_load(gcnt, __ATOMIC_ACQUIRE, __HIP_MEMORY_SCOPE_AGENT);
  }
  __syncthreads();
}

// ---- pack W (f32 [N][N]) into bf16 MFMA B-fragments, column-distributed ----
// granule u = [g:8][w:3][ki:4][lane:6]; block g owns cols [16g,16g+16), wave w
// owns K-eighth [512w,512w+512). lane: n = 16g+(lane&15), k = 512w+32ki+8*(lane>>4).
__global__ __launch_bounds__(256) void prep_kernel(const float* __restrict__ W,
                                                   unsigned short* __restrict__ wfrag) {
  unsigned u = blockIdx.x * 256u + threadIdx.x;        // < 2097152
  unsigned lane = u & 63u, lo = lane & 15u, hi = lane >> 4;
  unsigned ki = (u >> 6) & 15u;
  unsigned w = (u >> 10) & 7u;
  unsigned g = u >> 13;
  unsigned n = g * 16u + lo;
  unsigned k = w * 512u + ki * 32u + hi * 8u;
  const float* src = W + (size_t)n * 4096u + k;
  fl4 s0 = *(const fl4*)(src);
  fl4 s1 = *(const fl4*)(src + 4);
  us8 o;
  o[0] = f2bf(s0[0]); o[1] = f2bf(s0[1]); o[2] = f2bf(s0[2]); o[3] = f2bf(s0[3]);
  o[4] = f2bf(s1[0]); o[5] = f2bf(s1[1]); o[6] = f2bf(s1[2]); o[7] = f2bf(s1[3]);
  *(us8*)(wfrag + (size_t)u * 8u) = o;
}

__global__ __launch_bounds__(512, 2) void persist_kernel(
    const float* __restrict__ xin,     // [C][B][T]
    const float* __restrict__ state0,  // [B][N]
    const float* __restrict__ mask,    // [N]
    const float* __restrict__ enc,     // [C][N]
    const float* __restrict__ bias,    // [N]
    const float* __restrict__ decw,    // [C][N]
    const unsigned short* __restrict__ wfrag,
    unsigned short* __restrict__ zbuf, // [3][B][N] bf16
    float* __restrict__ dsc8,          // [8][C][B][T] f32, atomically accumulated
    int* __restrict__ cnt) {
  __shared__ float ldsP[8][64][17];    // per-wave K-partials

  const int tid = threadIdx.x;
  const int wave = tid >> 6;           // 0..7, owns K-eighth
  const int lane = tid & 63;
  const int lo = lane & 15, hi = lane >> 4;
  const int g = blockIdx.x;            // owns cols [16g, 16g+16)
  const int grp = g & 7;               // barrier group / dsc copy (XCD-ish)
  float* dscg = dsc8 + (size_t)grp * 131072u;

  // persistent W fragments: 16 x short8 = 64 VGPRs per thread
  short8 wf[16];
  {
    const short8* wp = (const short8*)wfrag + ((size_t)(g * 8 + wave) * 16u) * 64u + lane;
#pragma unroll
    for (int ki = 0; ki < 16; ++ki) wf[ki] = wp[(size_t)ki * 64u];
  }

  // update-phase role: row r = tid>>3 (0..63), col pair c2 = (tid&7)*2 of block's 16
  const int r = tid >> 3, c2 = (tid & 7) * 2;
  const int n0g = g * 16 + c2;
  const fl2 mk = *(const fl2*)(mask + n0g);
  const fl2 bi = *(const fl2*)(bias + n0g);
  const fl2 e0 = *(const fl2*)(enc + n0g);
  const fl2 e1 = *(const fl2*)(enc + 4096 + n0g);
  const fl2 e2 = *(const fl2*)(enc + 8192 + n0g);
  const fl2 e3 = *(const fl2*)(enc + 12288 + n0g);
  const fl2 w0 = *(const fl2*)(decw + n0g);
  const fl2 w1 = *(const fl2*)(decw + 4096 + n0g);
  const fl2 w2 = *(const fl2*)(decw + 8192 + n0g);
  const fl2 w3 = *(const fl2*)(decw + 12288 + n0g);
  const float* xp = xin + r * 512;     // x[c][r][t] = xp[c*32768 + t]
  const int kw = wave * 512;

  int ep = 0;

  // prologue: z_0 = state + mask*ext_0 (write-through)
  {
    fl2 st = *(const fl2*)(state0 + (size_t)r * 4096u + n0g);
    float x0 = xp[0], x1 = xp[32768], x2 = xp[65536], x3 = xp[98304];
    float z0 = st[0] + mk[0] * (x0 * e0[0] + x1 * e1[0] + x2 * e2[0] + x3 * e3[0]);
    float z1 = st[1] + mk[1] * (x0 * e0[1] + x1 * e1[1] + x2 * e2[1] + x3 * e3[1]);
    unsigned pack = (unsigned)f2bf(z0) | ((unsigned)f2bf(z1) << 16);
    __hip_atomic_store((unsigned*)(zbuf + (size_t)r * 4096u + n0g), pack,
                       __ATOMIC_RELAXED, __HIP_MEMORY_SCOPE_SYSTEM);
  }
  gbar(cnt, grp, ++ep);

  int buf = 0;
  for (int t = 0; t < 512; ++t) {
    // prefetch next-step x (consumed in phase B)
    float xv0 = 0.f, xv1 = 0.f, xv2 = 0.f, xv3 = 0.f;
    if (t < 511) {
      xv0 = xp[t + 1]; xv1 = xp[32768 + t + 1];
      xv2 = xp[65536 + t + 1]; xv3 = xp[98304 + t + 1];
    }

    // ---- MFMA: y_partial(own K-eighth) for [64 rows][16 cols], A from L2 ----
    fl4 acc0 = {0.f,0.f,0.f,0.f}, acc1 = acc0, acc2 = acc0, acc3 = acc0;
    const unsigned short* za = zbuf + (size_t)buf * ZELEMS + (size_t)lo * 4096u + kw + hi * 8;
#pragma unroll
    for (int ki = 0; ki < 16; ++ki) {
      short8 a0 = *(const short8*)(za + ki * 32);
      short8 a1 = *(const short8*)(za + ki * 32 + 16 * 4096);
      short8 a2 = *(const short8*)(za + ki * 32 + 32 * 4096);
      short8 a3 = *(const short8*)(za + ki * 32 + 48 * 4096);
      acc0 = __builtin_amdgcn_mfma_f32_16x16x32_bf16(a0, wf[ki], acc0, 0, 0, 0);
      acc1 = __builtin_amdgcn_mfma_f32_16x16x32_bf16(a1, wf[ki], acc1, 0, 0, 0);
      acc2 = __builtin_amdgcn_mfma_f32_16x16x32_bf16(a2, wf[ki], acc2, 0, 0, 0);
      acc3 = __builtin_amdgcn_mfma_f32_16x16x32_bf16(a3, wf[ki], acc3, 0, 0, 0);
    }
#pragma unroll
    for (int rr = 0; rr < 4; ++rr) {
      ldsP[wave][hi * 4 + rr][lo] = acc0[rr];
      ldsP[wave][16 + hi * 4 + rr][lo] = acc1[rr];
      ldsP[wave][32 + hi * 4 + rr][lo] = acc2[rr];
      ldsP[wave][48 + hi * 4 + rr][lo] = acc3[rr];
    }
    __syncthreads();

    // ---- reduce over 8 waves + state update ----
    float y0 = 0.f, y1 = 0.f;
#pragma unroll
    for (int w = 0; w < 8; ++w) { y0 += ldsP[w][r][c2]; y1 += ldsP[w][r][c2 + 1]; }
    float sn0 = mk[0] * (bi[0] + clipf(y0));
    float sn1 = mk[1] * (bi[1] + clipf(y1));

    // next z FIRST (critical path for step t+1), write-through
    if (t < 511) {
      int nb = buf + 1; if (nb == 3) nb = 0;
      float z0 = sn0 + mk[0] * (xv0 * e0[0] + xv1 * e1[0] + xv2 * e2[0] + xv3 * e3[0]);
      float z1 = sn1 + mk[1] * (xv0 * e0[1] + xv1 * e1[1] + xv2 * e2[1] + xv3 * e3[1]);
      unsigned pack = (unsigned)f2bf(z0) | ((unsigned)f2bf(z1) << 16);
      __hip_atomic_store((unsigned*)(zbuf + (size_t)nb * ZELEMS + (size_t)r * 4096u + n0g),
                         pack, __ATOMIC_RELAXED, __HIP_MEMORY_SCOPE_SYSTEM);
      buf = nb;
    }

    // decode partials into this group's copy (32-way fan-in, not 256)
    float d0 = sn0 * w0[0] + sn1 * w0[1];
    float d1 = sn0 * w1[0] + sn1 * w1[1];
    float d2 = sn0 * w2[0] + sn1 * w2[1];
    float d3 = sn0 * w3[0] + sn1 * w3[1];
    d0 += __shfl_xor(d0, 1); d0 += __shfl_xor(d0, 2); d0 += __shfl_xor(d0, 4);
    d1 += __shfl_xor(d1, 1); d1 += __shfl_xor(d1, 2); d1 += __shfl_xor(d1, 4);
    d2 += __shfl_xor(d2, 1); d2 += __shfl_xor(d2, 2); d2 += __shfl_xor(d2, 4);
    d3 += __shfl_xor(d3, 1); d3 += __shfl_xor(d3, 2); d3 += __shfl_xor(d3, 4);
    if ((tid & 7) == 0) {
      atomicAdd(dscg + r * 512 + t, d0);
      atomicAdd(dscg + 32768 + r * 512 + t, d1);
      atomicAdd(dscg + 65536 + r * 512 + t, d2);
      atomicAdd(dscg + 98304 + r * 512 + t, d3);
    }

    if (t < 511) gbar(cnt, grp, ++ep);
  }
}

__global__ __launch_bounds__(256) void final_kernel(const float* __restrict__ dsc8,
                                                    const float* __restrict__ decb,
                                                    float* __restrict__ out) {
  const unsigned u = blockIdx.x * 256u + threadIdx.x;  // < 131072, [C][B][T]
  const unsigned c = u >> 15;
  float s = decb[c];
#pragma unroll
  for (int g = 0; g < 8; ++g) s += dsc8[(size_t)g * 131072u + u];
  out[u] = clipf(s);
}

extern "C" void kernel_launch(void* const* d_in, const int* in_sizes, int n_in,
                              void* d_out, int out_size, void* d_ws, size_t ws_size,
                              hipStream_t stream) {
  const float* xin  = (const float*)d_in[0];
  const float* st   = (const float*)d_in[1];
  const float* mask = (const float*)d_in[2];
  const float* W    = (const float*)d_in[3];
  const float* enc  = (const float*)d_in[4];
  const float* bias = (const float*)d_in[5];
  const float* decw = (const float*)d_in[6];
  const float* decb = (const float*)d_in[7];
  char* ws = (char*)d_ws;
  unsigned short* wfrag = (unsigned short*)(ws + WFRAG_OFF);
  unsigned short* zbuf  = (unsigned short*)(ws + Z_OFF);
  float* dsc8 = (float*)(ws + DSC_OFF);
  int* cnt    = (int*)(ws + CNT_OFF);

  hipMemsetAsync(cnt, 0, 4096, stream);
  hipMemsetAsync(dsc8, 0, 4194304, stream);
  prep_kernel<<<8192, 256, 0, stream>>>(W, wfrag);
  persist_kernel<<<256, 512, 0, stream>>>(xin, st, mask, enc, bias, decw,
                                          wfrag, zbuf, dsc8, cnt);
  final_kernel<<<512, 256, 0, stream>>>(dsc8, decb, (float*)d_out);
}

// Round 4
// 11419.171 us; speedup vs baseline: 5.6770x; 1.0275x over previous
//
#include <hip/hip_runtime.h>
#include <stdint.h>

typedef __attribute__((ext_vector_type(8))) short short8;
typedef __attribute__((ext_vector_type(4))) float fl4;
typedef __attribute__((ext_vector_type(2))) float fl2;
typedef __attribute__((ext_vector_type(8))) unsigned short us8;

#define SAT_HI 1.0e6f
#define ZSLOT 262144u            // elements per z slot (64*4096 bf16)

__device__ __forceinline__ unsigned short f2bf(float f) {
  unsigned u = __float_as_uint(f);
  u += 0x7fffu + ((u >> 16) & 1u);   // RNE
  return (unsigned short)(u >> 16);
}
__device__ __forceinline__ float clipf(float x) {
  return fminf(fmaxf(x, 0.0f), SAT_HI);
}

// grid barrier: two-level relaxed arrival + relaxed poll.
// INV=false (monotone z ring): NO cache maintenance at all — z addresses are
// never reused within a launch, so no stale line can exist; producer stores
// are write-through (system-relaxed) so LLC always holds fresh data.
// INV=true (small-ws fallback, 3-slot ring): one acquire (buffer_inv)/epoch.
template <bool INV>
__device__ __forceinline__ void gbar(int* cbase, int grp, int ep) {
  __syncthreads();                  // compiler drains vmcnt for ALL waves here
  if (threadIdx.x == 0) {
    int* gcnt = cbase;
    int* xcnt = cbase + 32 + grp * 32;   // 128-byte separated lines
    int old = __hip_atomic_fetch_add(xcnt, 1, __ATOMIC_RELAXED, __HIP_MEMORY_SCOPE_AGENT);
    if (old == ep * 32 - 1)
      __hip_atomic_fetch_add(gcnt, 1, __ATOMIC_RELAXED, __HIP_MEMORY_SCOPE_AGENT);
    while (__hip_atomic_load(gcnt, __ATOMIC_RELAXED, __HIP_MEMORY_SCOPE_AGENT) < ep * 8)
      __builtin_amdgcn_s_sleep(2);
    if (INV)
      (void)__hip_atomic_load(gcnt, __ATOMIC_ACQUIRE, __HIP_MEMORY_SCOPE_AGENT);
  }
  __syncthreads();
}

// ---- pack W (f32 [N][N]) into bf16 MFMA B-fragments, column-distributed ----
// granule u = [g:8][w:3][ki:4][lane:6]; block g owns cols [16g,16g+16), wave w
// owns K-eighth [512w,512w+512). lane: n = 16g+(lane&15), k = 512w+32ki+8*(lane>>4).
__global__ __launch_bounds__(256) void prep_kernel(const float* __restrict__ W,
                                                   unsigned short* __restrict__ wfrag) {
  unsigned u = blockIdx.x * 256u + threadIdx.x;        // < 2097152
  unsigned lane = u & 63u, lo = lane & 15u, hi = lane >> 4;
  unsigned ki = (u >> 6) & 15u;
  unsigned w = (u >> 10) & 7u;
  unsigned g = u >> 13;
  unsigned n = g * 16u + lo;
  unsigned k = w * 512u + ki * 32u + hi * 8u;
  const float* src = W + (size_t)n * 4096u + k;
  fl4 s0 = *(const fl4*)(src);
  fl4 s1 = *(const fl4*)(src + 4);
  us8 o;
  o[0] = f2bf(s0[0]); o[1] = f2bf(s0[1]); o[2] = f2bf(s0[2]); o[3] = f2bf(s0[3]);
  o[4] = f2bf(s1[0]); o[5] = f2bf(s1[1]); o[6] = f2bf(s1[2]); o[7] = f2bf(s1[3]);
  *(us8*)(wfrag + (size_t)u * 8u) = o;
}

template <bool INV>
__global__ __launch_bounds__(512, 2) void persist_kernel(
    const float* __restrict__ xin,     // [C][B][T]
    const float* __restrict__ state0,  // [B][N]
    const float* __restrict__ mask,    // [N]
    const float* __restrict__ enc,     // [C][N]
    const float* __restrict__ bias,    // [N]
    const float* __restrict__ decw,    // [C][N]
    const unsigned short* __restrict__ wfrag,
    unsigned short* __restrict__ zbuf, // [RING][B][N] bf16
    float* __restrict__ dsc8,          // [8][C][B][T] f32, atomically accumulated
    int* __restrict__ cnt) {
  __shared__ float ldsP[8][64][17];    // per-wave K-partials

  const int tid = threadIdx.x;
  const int wave = tid >> 6;           // 0..7, owns K-eighth
  const int lane = tid & 63;
  const int lo = lane & 15, hi = lane >> 4;
  const int g = blockIdx.x;            // owns cols [16g, 16g+16)
  const int grp = g & 7;               // barrier group / dsc copy (XCD-ish)
  float* dscg = dsc8 + (size_t)grp * 131072u;

  // persistent W fragments: 16 x short8 = 64 VGPRs per thread
  short8 wf[16];
  {
    const short8* wp = (const short8*)wfrag + ((size_t)(g * 8 + wave) * 16u) * 64u + lane;
#pragma unroll
    for (int ki = 0; ki < 16; ++ki) wf[ki] = wp[(size_t)ki * 64u];
  }

  // update-phase role: row r = tid>>3 (0..63), col pair c2 = (tid&7)*2 of block's 16
  const int r = tid >> 3, c2 = (tid & 7) * 2;
  const int n0g = g * 16 + c2;
  const fl2 mk = *(const fl2*)(mask + n0g);
  const fl2 bi = *(const fl2*)(bias + n0g);
  const fl2 e0 = *(const fl2*)(enc + n0g);
  const fl2 e1 = *(const fl2*)(enc + 4096 + n0g);
  const fl2 e2 = *(const fl2*)(enc + 8192 + n0g);
  const fl2 e3 = *(const fl2*)(enc + 12288 + n0g);
  const fl2 w0 = *(const fl2*)(decw + n0g);
  const fl2 w1 = *(const fl2*)(decw + 4096 + n0g);
  const fl2 w2 = *(const fl2*)(decw + 8192 + n0g);
  const fl2 w3 = *(const fl2*)(decw + 12288 + n0g);
  const float* xp = xin + r * 512;     // x[c][r][t] = xp[c*32768 + t]
  const int kw = wave * 512;

  int ep = 0;

  // prologue: z_0 -> slot 0 (write-through)
  {
    fl2 st = *(const fl2*)(state0 + (size_t)r * 4096u + n0g);
    float x0 = xp[0], x1 = xp[32768], x2 = xp[65536], x3 = xp[98304];
    float z0 = st[0] + mk[0] * (x0 * e0[0] + x1 * e1[0] + x2 * e2[0] + x3 * e3[0]);
    float z1 = st[1] + mk[1] * (x0 * e0[1] + x1 * e1[1] + x2 * e2[1] + x3 * e3[1]);
    unsigned pack = (unsigned)f2bf(z0) | ((unsigned)f2bf(z1) << 16);
    __hip_atomic_store((unsigned*)(zbuf + (size_t)r * 4096u + n0g), pack,
                       __ATOMIC_RELAXED, __HIP_MEMORY_SCOPE_SYSTEM);
  }
  gbar<INV>(cnt, grp, ++ep);

  float pd0 = 0.f, pd1 = 0.f, pd2 = 0.f, pd3 = 0.f;  // deferred decode (for t-1)
  int slot = 0;
  for (int t = 0; t < 512; ++t) {
    // issue previous step's decode atomics now: their LLC ack drains at the
    // post-MFMA __syncthreads (hidden), not in the pre-barrier drain.
    if (t > 0 && (tid & 7) == 0) {
      atomicAdd(dscg + r * 512 + (t - 1), pd0);
      atomicAdd(dscg + 32768 + r * 512 + (t - 1), pd1);
      atomicAdd(dscg + 65536 + r * 512 + (t - 1), pd2);
      atomicAdd(dscg + 98304 + r * 512 + (t - 1), pd3);
    }
    // prefetch next-step x
    float xv0 = 0.f, xv1 = 0.f, xv2 = 0.f, xv3 = 0.f;
    if (t < 511) {
      xv0 = xp[t + 1]; xv1 = xp[32768 + t + 1];
      xv2 = xp[65536 + t + 1]; xv3 = xp[98304 + t + 1];
    }

    // ---- MFMA: y_partial(own K-eighth) for [64 rows][16 cols], A from L2 ----
    fl4 acc0 = {0.f,0.f,0.f,0.f}, acc1 = acc0, acc2 = acc0, acc3 = acc0;
    const unsigned short* za = zbuf + (size_t)slot * ZSLOT + (size_t)lo * 4096u + kw + hi * 8;
#pragma unroll
    for (int ki = 0; ki < 16; ++ki) {
      short8 a0 = *(const short8*)(za + ki * 32);
      short8 a1 = *(const short8*)(za + ki * 32 + 16 * 4096);
      short8 a2 = *(const short8*)(za + ki * 32 + 32 * 4096);
      short8 a3 = *(const short8*)(za + ki * 32 + 48 * 4096);
      acc0 = __builtin_amdgcn_mfma_f32_16x16x32_bf16(a0, wf[ki], acc0, 0, 0, 0);
      acc1 = __builtin_amdgcn_mfma_f32_16x16x32_bf16(a1, wf[ki], acc1, 0, 0, 0);
      acc2 = __builtin_amdgcn_mfma_f32_16x16x32_bf16(a2, wf[ki], acc2, 0, 0, 0);
      acc3 = __builtin_amdgcn_mfma_f32_16x16x32_bf16(a3, wf[ki], acc3, 0, 0, 0);
    }
#pragma unroll
    for (int rr = 0; rr < 4; ++rr) {
      ldsP[wave][hi * 4 + rr][lo] = acc0[rr];
      ldsP[wave][16 + hi * 4 + rr][lo] = acc1[rr];
      ldsP[wave][32 + hi * 4 + rr][lo] = acc2[rr];
      ldsP[wave][48 + hi * 4 + rr][lo] = acc3[rr];
    }
    __syncthreads();

    // ---- reduce over 8 waves + state update ----
    float y0 = 0.f, y1 = 0.f;
#pragma unroll
    for (int w = 0; w < 8; ++w) { y0 += ldsP[w][r][c2]; y1 += ldsP[w][r][c2 + 1]; }
    float sn0 = mk[0] * (bi[0] + clipf(y0));
    float sn1 = mk[1] * (bi[1] + clipf(y1));

    // next z FIRST (critical path for step t+1), write-through
    if (t < 511) {
      int ns;
      if (INV) { ns = slot + 1; if (ns == 3) ns = 0; }
      else     { ns = t + 1; }
      float z0 = sn0 + mk[0] * (xv0 * e0[0] + xv1 * e1[0] + xv2 * e2[0] + xv3 * e3[0]);
      float z1 = sn1 + mk[1] * (xv0 * e0[1] + xv1 * e1[1] + xv2 * e2[1] + xv3 * e3[1]);
      unsigned pack = (unsigned)f2bf(z0) | ((unsigned)f2bf(z1) << 16);
      __hip_atomic_store((unsigned*)(zbuf + (size_t)ns * ZSLOT + (size_t)r * 4096u + n0g),
                         pack, __ATOMIC_RELAXED, __HIP_MEMORY_SCOPE_SYSTEM);
      slot = ns;
    }

    // decode partials -> registers (issued after next barrier)
    float d0 = sn0 * w0[0] + sn1 * w0[1];
    float d1 = sn0 * w1[0] + sn1 * w1[1];
    float d2 = sn0 * w2[0] + sn1 * w2[1];
    float d3 = sn0 * w3[0] + sn1 * w3[1];
    d0 += __shfl_xor(d0, 1); d0 += __shfl_xor(d0, 2); d0 += __shfl_xor(d0, 4);
    d1 += __shfl_xor(d1, 1); d1 += __shfl_xor(d1, 2); d1 += __shfl_xor(d1, 4);
    d2 += __shfl_xor(d2, 1); d2 += __shfl_xor(d2, 2); d2 += __shfl_xor(d2, 4);
    d3 += __shfl_xor(d3, 1); d3 += __shfl_xor(d3, 2); d3 += __shfl_xor(d3, 4);
    pd0 = d0; pd1 = d1; pd2 = d2; pd3 = d3;

    if (t < 511) gbar<INV>(cnt, grp, ++ep);
  }
  // flush last step's decode
  if ((tid & 7) == 0) {
    atomicAdd(dscg + r * 512 + 511, pd0);
    atomicAdd(dscg + 32768 + r * 512 + 511, pd1);
    atomicAdd(dscg + 65536 + r * 512 + 511, pd2);
    atomicAdd(dscg + 98304 + r * 512 + 511, pd3);
  }
}

__global__ __launch_bounds__(256) void final_kernel(const float* __restrict__ dsc8,
                                                    const float* __restrict__ decb,
                                                    float* __restrict__ out) {
  const unsigned u = blockIdx.x * 256u + threadIdx.x;  // < 131072, [C][B][T]
  const unsigned c = u >> 15;
  float s = decb[c];
#pragma unroll
  for (int g = 0; g < 8; ++g) s += dsc8[(size_t)g * 131072u + u];
  out[u] = clipf(s);
}

extern "C" void kernel_launch(void* const* d_in, const int* in_sizes, int n_in,
                              void* d_out, int out_size, void* d_ws, size_t ws_size,
                              hipStream_t stream) {
  const float* xin  = (const float*)d_in[0];
  const float* st   = (const float*)d_in[1];
  const float* mask = (const float*)d_in[2];
  const float* W    = (const float*)d_in[3];
  const float* enc  = (const float*)d_in[4];
  const float* bias = (const float*)d_in[5];
  const float* decw = (const float*)d_in[6];
  const float* decb = (const float*)d_in[7];
  char* ws = (char*)d_ws;

  const size_t WFRAG_B = 33554432ull;             // 32 MB
  const size_t SLOT_B  = 524288ull;               // 512 KB per z slot
  const size_t DSC_B   = 4194304ull;              // 8 copies x 512 KB
  const size_t CNT_B   = 4096ull;
  const size_t need_big = WFRAG_B + 513ull * SLOT_B + DSC_B + CNT_B;  // ~306.7 MB

  unsigned short* wfrag = (unsigned short*)(ws);
  prep_kernel<<<8192, 256, 0, stream>>>(W, wfrag);

  if (ws_size >= need_big) {
    unsigned short* zbuf = (unsigned short*)(ws + WFRAG_B);
    float* dsc8 = (float*)(ws + WFRAG_B + 513ull * SLOT_B);
    int* cnt    = (int*)(ws + WFRAG_B + 513ull * SLOT_B + DSC_B);
    hipMemsetAsync(cnt, 0, CNT_B, stream);
    hipMemsetAsync(dsc8, 0, DSC_B, stream);
    persist_kernel<false><<<256, 512, 0, stream>>>(xin, st, mask, enc, bias, decw,
                                                   wfrag, zbuf, dsc8, cnt);
    final_kernel<<<512, 256, 0, stream>>>(dsc8, decb, (float*)d_out);
  } else {
    unsigned short* zbuf = (unsigned short*)(ws + WFRAG_B);
    float* dsc8 = (float*)(ws + WFRAG_B + 3ull * SLOT_B);
    int* cnt    = (int*)(ws + WFRAG_B + 3ull * SLOT_B + DSC_B);
    hipMemsetAsync(cnt, 0, CNT_B, stream);
    hipMemsetAsync(dsc8, 0, DSC_B, stream);
    persist_kernel<true><<<256, 512, 0, stream>>>(xin, st, mask, enc, bias, decw,
                                                  wfrag, zbuf, dsc8, cnt);
    final_kernel<<<512, 256, 0, stream>>>(dsc8, decb, (float*)d_out);
  }
}

// Round 5
// 6590.648 us; speedup vs baseline: 9.8362x; 1.7326x over previous
//
#include <hip/hip_runtime.h>
#include <stdint.h>

typedef __attribute__((ext_vector_type(8))) short short8;
typedef __attribute__((ext_vector_type(4))) float fl4;
typedef __attribute__((ext_vector_type(2))) float fl2;
typedef __attribute__((ext_vector_type(8))) unsigned short us8;

#define SAT_HI 1.0e6f
#define ZSLOT 262144u            // elements per z slot (64*4096 bf16)

__device__ __forceinline__ unsigned short f2bf(float f) {
  unsigned u = __float_as_uint(f);
  u += 0x7fffu + ((u >> 16) & 1u);   // RNE
  return (unsigned short)(u >> 16);
}
__device__ __forceinline__ float clipf(float x) {
  return fminf(fmaxf(x, 0.0f), SAT_HI);
}

__device__ __forceinline__ void gload16(const void* g, void* l) {
  __builtin_amdgcn_global_load_lds(
      (const __attribute__((address_space(1))) void*)g,
      (__attribute__((address_space(3))) void*)l, 16, 0, 0);
}

// grid barrier: two-level relaxed arrival + relaxed poll.
// INV=false (monotone z ring): no cache maintenance (addresses never reused).
// INV=true (small-ws fallback, 3-slot ring): one acquire (buffer_inv)/epoch.
template <bool INV>
__device__ __forceinline__ void gbar(int* cbase, int grp, int ep) {
  __syncthreads();
  if (threadIdx.x == 0) {
    int* gcnt = cbase;
    int* xcnt = cbase + 32 + grp * 32;   // 128-byte separated lines
    int old = __hip_atomic_fetch_add(xcnt, 1, __ATOMIC_RELAXED, __HIP_MEMORY_SCOPE_AGENT);
    if (old == ep * 32 - 1)
      __hip_atomic_fetch_add(gcnt, 1, __ATOMIC_RELAXED, __HIP_MEMORY_SCOPE_AGENT);
    while (__hip_atomic_load(gcnt, __ATOMIC_RELAXED, __HIP_MEMORY_SCOPE_AGENT) < ep * 8)
      __builtin_amdgcn_s_sleep(1);
    if (INV)
      (void)__hip_atomic_load(gcnt, __ATOMIC_ACQUIRE, __HIP_MEMORY_SCOPE_AGENT);
  }
  __syncthreads();
}

// ---- pack W (f32 [N][N]) into bf16 MFMA B-fragments, column-distributed ----
// granule u = [g:8][w:3][ki:4][lane:6]; block g owns cols [16g,16g+16), wave w
// owns K-eighth [512w,512w+512). lane: n = 16g+(lane&15), k = 512w+32ki+8*(lane>>4).
__global__ __launch_bounds__(256) void prep_kernel(const float* __restrict__ W,
                                                   unsigned short* __restrict__ wfrag) {
  unsigned u = blockIdx.x * 256u + threadIdx.x;        // < 2097152
  unsigned lane = u & 63u, lo = lane & 15u, hi = lane >> 4;
  unsigned ki = (u >> 6) & 15u;
  unsigned w = (u >> 10) & 7u;
  unsigned g = u >> 13;
  unsigned n = g * 16u + lo;
  unsigned k = w * 512u + ki * 32u + hi * 8u;
  const float* src = W + (size_t)n * 4096u + k;
  fl4 s0 = *(const fl4*)(src);
  fl4 s1 = *(const fl4*)(src + 4);
  us8 o;
  o[0] = f2bf(s0[0]); o[1] = f2bf(s0[1]); o[2] = f2bf(s0[2]); o[3] = f2bf(s0[3]);
  o[4] = f2bf(s1[0]); o[5] = f2bf(s1[1]); o[6] = f2bf(s1[2]); o[7] = f2bf(s1[3]);
  *(us8*)(wfrag + (size_t)u * 8u) = o;
}

template <bool INV>
__global__ __launch_bounds__(512, 2) void persist_kernel(
    const float* __restrict__ xin,     // [C][B][T]
    const float* __restrict__ state0,  // [B][N]
    const float* __restrict__ mask,    // [N]
    const float* __restrict__ enc,     // [C][N]
    const float* __restrict__ bias,    // [N]
    const float* __restrict__ decw,    // [C][N]
    const unsigned short* __restrict__ wfrag,
    unsigned short* __restrict__ zbuf, // [RING][B][N] bf16
    float* __restrict__ dsc8,          // [8][C][B][T] f32, atomically accumulated
    int* __restrict__ cnt) {
  // per-wave 16 KB stage buffers (8 x 16 KB = 128 KB); after MFMA each wave's
  // f32 partial block [64][17] (4352 B) is aliased into its OWN stage buffer.
  __shared__ __align__(16) unsigned char sm[131072 + 128];
  float* dred = (float*)(sm + 131072);

  const int tid = threadIdx.x;
  const int wave = tid >> 6;           // 0..7, owns K-eighth
  const int lane = tid & 63;
  const int lo = lane & 15, hi = lane >> 4;
  const int g = blockIdx.x;            // owns cols [16g, 16g+16)
  const int grp = g & 7;               // barrier group / dsc copy (XCD-ish)
  float* dscg = dsc8 + (size_t)grp * 131072u;
  // per-block rotation of stage order: decorrelate same-XCD blocks' L2 fills
  const int mrot = (g >> 3) & 3;
  const int jrot = ((g >> 5) & 3) << 2;

  // persistent W fragments: 16 x short8 = 64 VGPRs per thread
  short8 wf[16];
  {
    const short8* wp = (const short8*)wfrag + ((size_t)(g * 8 + wave) * 16u) * 64u + lane;
#pragma unroll
    for (int ki = 0; ki < 16; ++ki) wf[ki] = wp[(size_t)ki * 64u];
  }

  // update-phase role: row r = tid>>3 (0..63), col pair c2 = (tid&7)*2
  const int r = tid >> 3, c2 = (tid & 7) * 2;
  const int n0g = g * 16 + c2;
  const fl2 mk = *(const fl2*)(mask + n0g);
  const fl2 bi = *(const fl2*)(bias + n0g);
  const fl2 e0 = *(const fl2*)(enc + n0g);
  const fl2 e1 = *(const fl2*)(enc + 4096 + n0g);
  const fl2 e2 = *(const fl2*)(enc + 8192 + n0g);
  const fl2 e3 = *(const fl2*)(enc + 12288 + n0g);
  const fl2 w0 = *(const fl2*)(decw + n0g);
  const fl2 w1 = *(const fl2*)(decw + 4096 + n0g);
  const fl2 w2 = *(const fl2*)(decw + 8192 + n0g);
  const fl2 w3 = *(const fl2*)(decw + 12288 + n0g);
  const float* xp = xin + r * 512;     // x[c][r][t] = xp[c*32768 + t]
  const int kwb = wave * 1024;         // byte offset of this wave's K-eighth

  char* mybuf = (char*)sm + wave * 16384;
  float* pown = (float*)mybuf;         // aliased partial region [64][17] f32

  int ep = 0;

  // prologue: z_0 -> slot 0 (write-through)
  {
    fl2 st = *(const fl2*)(state0 + (size_t)r * 4096u + n0g);
    float x0 = xp[0], x1 = xp[32768], x2 = xp[65536], x3 = xp[98304];
    float z0 = st[0] + mk[0] * (x0 * e0[0] + x1 * e1[0] + x2 * e2[0] + x3 * e3[0]);
    float z1 = st[1] + mk[1] * (x0 * e0[1] + x1 * e1[1] + x2 * e2[1] + x3 * e3[1]);
    unsigned pack = (unsigned)f2bf(z0) | ((unsigned)f2bf(z1) << 16);
    __hip_atomic_store((unsigned*)(zbuf + (size_t)r * 4096u + n0g), pack,
                       __ATOMIC_RELAXED, __HIP_MEMORY_SCOPE_SYSTEM);
  }
  gbar<INV>(cnt, grp, ++ep);

  float pd0 = 0.f, pd1 = 0.f, pd2 = 0.f, pd3 = 0.f;  // deferred decode (t-1)
  int slot = 0;
  for (int t = 0; t < 512; ++t) {
    // previous step's decode atomics: fire-and-forget, drain under phase A
    if (t > 0 && (tid & 7) == 0) {
      atomicAdd(dscg + r * 512 + (t - 1), pd0);
      atomicAdd(dscg + 32768 + r * 512 + (t - 1), pd1);
      atomicAdd(dscg + 65536 + r * 512 + (t - 1), pd2);
      atomicAdd(dscg + 98304 + r * 512 + (t - 1), pd3);
    }
    // prefetch next-step x
    float xv0 = 0.f, xv1 = 0.f, xv2 = 0.f, xv3 = 0.f;
    if (t < 511) {
      xv0 = xp[t + 1]; xv1 = xp[32768 + t + 1];
      xv2 = xp[65536 + t + 1]; xv3 = xp[98304 + t + 1];
    }

    // ---- phase A: self-staged gload_lds stream + MFMA from LDS ----
    // acc[mtx] accumulates row-tile mt=(mtx+mrot)&3 (static reg index, rule #20)
    const char* zsrc = (const char*)(zbuf + (size_t)slot * ZSLOT) + kwb;
    fl4 acc[4];
#pragma unroll
    for (int i = 0; i < 4; ++i) acc[i] = (fl4){0.f, 0.f, 0.f, 0.f};
#pragma unroll
    for (int mtx = 0; mtx < 4; ++mtx) {
      const int mt = (mtx + mrot) & 3;
      // stage 16 rows x 1 KB (this wave's K-eighth), XOR-swizzled source
#pragma unroll
      for (int jx = 0; jx < 16; ++jx) {
        const int j = (jx + jrot) & 15;
        const int row = mt * 16 + j;
        gload16(zsrc + (size_t)row * 8192 + (((unsigned)lane ^ (unsigned)(j & 7)) << 4),
                mybuf + j * 1024);
      }
      asm volatile("s_waitcnt vmcnt(0)" ::: "memory");
      __builtin_amdgcn_sched_barrier(0);
#pragma unroll
      for (int ki = 0; ki < 16; ++ki) {
        short8 a = *(const short8*)(mybuf + lo * 1024 +
                                    ((ki * 64 + hi * 16) ^ ((lo & 7) << 4)));
        acc[mtx] = __builtin_amdgcn_mfma_f32_16x16x32_bf16(a, wf[ki], acc[mtx], 0, 0, 0);
      }
    }
    // stash partials into own stage buffer (aliased; own MFMA reads complete
    // per lgkmcnt dependency before these writes issue)
#pragma unroll
    for (int mtx = 0; mtx < 4; ++mtx) {
      const int mt = (mtx + mrot) & 3;
#pragma unroll
      for (int rr = 0; rr < 4; ++rr)
        pown[(mt * 16 + hi * 4 + rr) * 17 + lo] = acc[mtx][rr];
    }
    __syncthreads();

    // ---- phase B: reduce over 8 waves + state update ----
    float y0 = 0.f, y1 = 0.f;
#pragma unroll
    for (int w = 0; w < 8; ++w) {
      const float* pw = (const float*)((const char*)sm + w * 16384);
      y0 += pw[r * 17 + c2];
      y1 += pw[r * 17 + c2 + 1];
    }
    float sn0 = mk[0] * (bi[0] + clipf(y0));
    float sn1 = mk[1] * (bi[1] + clipf(y1));

    // next z FIRST (critical path for step t+1), write-through
    if (t < 511) {
      int ns;
      if (INV) { ns = slot + 1; if (ns == 3) ns = 0; }
      else     { ns = t + 1; }
      float z0 = sn0 + mk[0] * (xv0 * e0[0] + xv1 * e1[0] + xv2 * e2[0] + xv3 * e3[0]);
      float z1 = sn1 + mk[1] * (xv0 * e0[1] + xv1 * e1[1] + xv2 * e2[1] + xv3 * e3[1]);
      unsigned pack = (unsigned)f2bf(z0) | ((unsigned)f2bf(z1) << 16);
      __hip_atomic_store((unsigned*)(zbuf + (size_t)ns * ZSLOT + (size_t)r * 4096u + n0g),
                         pack, __ATOMIC_RELAXED, __HIP_MEMORY_SCOPE_SYSTEM);
      slot = ns;
    }

    // decode partials -> registers (atomics issued after next barrier)
    float d0 = sn0 * w0[0] + sn1 * w0[1];
    float d1 = sn0 * w1[0] + sn1 * w1[1];
    float d2 = sn0 * w2[0] + sn1 * w2[1];
    float d3 = sn0 * w3[0] + sn1 * w3[1];
    d0 += __shfl_xor(d0, 1); d0 += __shfl_xor(d0, 2); d0 += __shfl_xor(d0, 4);
    d1 += __shfl_xor(d1, 1); d1 += __shfl_xor(d1, 2); d1 += __shfl_xor(d1, 4);
    d2 += __shfl_xor(d2, 1); d2 += __shfl_xor(d2, 2); d2 += __shfl_xor(d2, 4);
    d3 += __shfl_xor(d3, 1); d3 += __shfl_xor(d3, 2); d3 += __shfl_xor(d3, 4);
    pd0 = d0; pd1 = d1; pd2 = d2; pd3 = d3;
    (void)dred;

    if (t < 511) gbar<INV>(cnt, grp, ++ep);
  }
  // flush last step's decode
  if ((tid & 7) == 0) {
    atomicAdd(dscg + r * 512 + 511, pd0);
    atomicAdd(dscg + 32768 + r * 512 + 511, pd1);
    atomicAdd(dscg + 65536 + r * 512 + 511, pd2);
    atomicAdd(dscg + 98304 + r * 512 + 511, pd3);
  }
}

__global__ __launch_bounds__(256) void final_kernel(const float* __restrict__ dsc8,
                                                    const float* __restrict__ decb,
                                                    float* __restrict__ out) {
  const unsigned u = blockIdx.x * 256u + threadIdx.x;  // < 131072, [C][B][T]
  const unsigned c = u >> 15;
  float s = decb[c];
#pragma unroll
  for (int g = 0; g < 8; ++g) s += dsc8[(size_t)g * 131072u + u];
  out[u] = clipf(s);
}

extern "C" void kernel_launch(void* const* d_in, const int* in_sizes, int n_in,
                              void* d_out, int out_size, void* d_ws, size_t ws_size,
                              hipStream_t stream) {
  const float* xin  = (const float*)d_in[0];
  const float* st   = (const float*)d_in[1];
  const float* mask = (const float*)d_in[2];
  const float* W    = (const float*)d_in[3];
  const float* enc  = (const float*)d_in[4];
  const float* bias = (const float*)d_in[5];
  const float* decw = (const float*)d_in[6];
  const float* decb = (const float*)d_in[7];
  char* ws = (char*)d_ws;

  const size_t WFRAG_B = 33554432ull;             // 32 MB
  const size_t SLOT_B  = 524288ull;               // 512 KB per z slot
  const size_t DSC_B   = 4194304ull;              // 8 copies x 512 KB
  const size_t CNT_B   = 4096ull;
  const size_t need_big = WFRAG_B + 513ull * SLOT_B + DSC_B + CNT_B;  // ~306.7 MB

  unsigned short* wfrag = (unsigned short*)(ws);
  prep_kernel<<<8192, 256, 0, stream>>>(W, wfrag);

  if (ws_size >= need_big) {
    unsigned short* zbuf = (unsigned short*)(ws + WFRAG_B);
    float* dsc8 = (float*)(ws + WFRAG_B + 513ull * SLOT_B);
    int* cnt    = (int*)(ws + WFRAG_B + 513ull * SLOT_B + DSC_B);
    hipMemsetAsync(cnt, 0, CNT_B, stream);
    hipMemsetAsync(dsc8, 0, DSC_B, stream);
    persist_kernel<false><<<256, 512, 0, stream>>>(xin, st, mask, enc, bias, decw,
                                                   wfrag, zbuf, dsc8, cnt);
    final_kernel<<<512, 256, 0, stream>>>(dsc8, decb, (float*)d_out);
  } else {
    unsigned short* zbuf = (unsigned short*)(ws + WFRAG_B);
    float* dsc8 = (float*)(ws + WFRAG_B + 3ull * SLOT_B);
    int* cnt    = (int*)(ws + WFRAG_B + 3ull * SLOT_B + DSC_B);
    hipMemsetAsync(cnt, 0, CNT_B, stream);
    hipMemsetAsync(dsc8, 0, DSC_B, stream);
    persist_kernel<true><<<256, 512, 0, stream>>>(xin, st, mask, enc, bias, decw,
                                                  wfrag, zbuf, dsc8, cnt);
    final_kernel<<<512, 256, 0, stream>>>(dsc8, decb, (float*)d_out);
  }
}